// Round 1
// baseline (813.661 us; speedup 1.0000x reference)
//
#include <hip/hip_runtime.h>
#include <stdint.h>

#define NPTS 262144
#define KOFF 27
#define EPS 1e-5f

typedef __attribute__((ext_vector_type(8))) short short8;
typedef __attribute__((ext_vector_type(4))) float floatx4;

__device__ __forceinline__ floatx4 mfma16(short8 a, short8 b, floatx4 c) {
    return __builtin_amdgcn_mfma_f32_16x16x32_bf16(a, b, c, 0, 0, 0);
}

__device__ __forceinline__ uint16_t f2bf(float f) {
    union { float f; uint32_t u; } v; v.f = f;
    return (uint16_t)((v.u + 0x7FFFu + ((v.u >> 16) & 1u)) >> 16);
}

// ---------------------------------------------------------------- prep
// Weight transposes to bf16 [n][k] (B-fragment wants 8 contiguous k per n),
// and zero the 64-bank stat accumulators.
__global__ void k_prep(const float* __restrict__ W1a, const float* __restrict__ W3,
                       const float* __restrict__ W1b, uint16_t* __restrict__ w1aT,
                       uint16_t* __restrict__ w3T, uint16_t* __restrict__ w1bT,
                       float* __restrict__ stats) {
    int t = blockIdx.x * 256 + threadIdx.x;
    int stride = gridDim.x * 256;
    for (int i = t; i < 64 * 256; i += stride) {        // w1aT[n*256+k] = W1a[k*64+n]
        int n = i >> 8, k = i & 255;
        w1aT[i] = f2bf(W1a[k * 64 + n]);
    }
    for (int i = t; i < KOFF * 64 * 64; i += stride) {  // w3T[kk][o*64+in] = W3[kk][in][o]
        int kk = i >> 12; int r = i & 4095; int o = r >> 6; int in_ = r & 63;
        w3T[i] = f2bf(W3[kk * 4096 + in_ * 64 + o]);
    }
    for (int i = t; i < 256 * 64; i += stride) {        // w1bT[n*64+k] = W1b[k*256+n]
        int n = i >> 6, k = i & 63;
        w1bT[i] = f2bf(W1b[k * 256 + n]);
    }
    for (int i = t; i < 64 * 768; i += stride) stats[i] = 0.f;
}

// ---------------------------------------------------------------- gemm1
// y1 = x @ W1a  (N x 256 @ 256 x 64), + BN1 stat accumulation.
// 64 points/block, 4 waves, each wave: 16 pts x 64 outch, K=256 (8 ksteps).
__global__ __launch_bounds__(256) void k_gemm1(const float* __restrict__ x,
        const uint16_t* __restrict__ w1aT, float* __restrict__ y,
        float* __restrict__ stats) {
    __shared__ uint16_t xs[64 * 264];   // pad 256->264: 2-way bank alias (free)
    __shared__ float ssum[64], ssq[64];
    const int t = threadIdx.x;
    const int base = blockIdx.x * 64;
    const float4* xv = (const float4*)(x + (size_t)base * 256);
#pragma unroll
    for (int i = 0; i < 16; ++i) {
        int f = t + 256 * i;            // float4 idx in 64x64-float4 tile
        int r = f >> 6, c4 = f & 63;
        float4 v = xv[f];
        uint32_t lo = (uint32_t)f2bf(v.x) | ((uint32_t)f2bf(v.y) << 16);
        uint32_t hi = (uint32_t)f2bf(v.z) | ((uint32_t)f2bf(v.w) << 16);
        uint32_t* dst = (uint32_t*)&xs[r * 264 + c4 * 4];
        dst[0] = lo; dst[1] = hi;
    }
    if (t < 64) { ssum[t] = 0.f; ssq[t] = 0.f; }
    __syncthreads();
    const int wave = t >> 6, lane = t & 63;
    const int m = lane & 15, quad = lane >> 4;
    floatx4 zero = {0.f, 0.f, 0.f, 0.f};
    floatx4 acc[4] = {zero, zero, zero, zero};
    const uint16_t* arow = &xs[(wave * 16 + m) * 264 + quad * 8];
#pragma unroll
    for (int ks = 0; ks < 8; ++ks) {
        short8 a = *(const short8*)(arow + ks * 32);
#pragma unroll
        for (int nf = 0; nf < 4; ++nf) {
            // B from global: 32KB, L2-resident, shared by all blocks
            short8 b = *(const short8*)(w1aT + (nf * 16 + m) * 256 + ks * 32 + quad * 8);
            acc[nf] = mfma16(a, b, acc[nf]);
        }
    }
    const int bank = blockIdx.x & 63;
    float* sb = stats + bank * 768;
#pragma unroll
    for (int nf = 0; nf < 4; ++nf) {
        float s = 0.f, q = 0.f;
#pragma unroll
        for (int r = 0; r < 4; ++r) {
            float v = acc[nf][r];
            int pt = base + wave * 16 + quad * 4 + r;   // C/D: row=quad*4+reg
            y[(size_t)pt * 64 + nf * 16 + m] = v;        //      col=lane&15
            s += v; q += v * v;
        }
        s += __shfl_xor(s, 16); q += __shfl_xor(q, 16);
        s += __shfl_xor(s, 32); q += __shfl_xor(q, 32);
        if (quad == 0) { atomicAdd(&ssum[nf * 16 + m], s); atomicAdd(&ssq[nf * 16 + m], q); }
    }
    __syncthreads();
    if (t < 64) { atomicAdd(&sb[t], ssum[t]); atomicAdd(&sb[64 + t], ssq[t]); }
}

// ---------------------------------------------------------------- BN finalize
__global__ void k_fin(const float* __restrict__ stats, const float* __restrict__ g,
                      const float* __restrict__ bta, float* __restrict__ consts,
                      int nch, int soff, int coff) {
    int c = blockIdx.x * blockDim.x + threadIdx.x;
    if (c >= nch) return;
    float s = 0.f, q = 0.f;
    for (int b = 0; b < 64; ++b) {
        s += stats[b * 768 + soff + c];
        q += stats[b * 768 + soff + nch + c];
    }
    float mean = s / (float)NPTS;
    float var = q / (float)NPTS - mean * mean;
    float sc = g[c] * rsqrtf(var + EPS);
    consts[coff + c] = sc;
    consts[coff + nch + c] = bta[c] - mean * sc;
}

// ---------------------------------------------------------------- bn+relu -> bf16
__global__ __launch_bounds__(256) void k_bnrelu(const float* __restrict__ y,
        const float* __restrict__ consts, uint16_t* __restrict__ h) {
    int t = blockIdx.x * 256 + threadIdx.x;
    size_t off = (size_t)t * 8;
    float4 v0 = *(const float4*)(y + off);
    float4 v1 = *(const float4*)(y + off + 4);
    int cbase = (int)(off & 63);
    float vs[8] = {v0.x, v0.y, v0.z, v0.w, v1.x, v1.y, v1.z, v1.w};
    union { uint16_t u[8]; uint4 v; } r;
#pragma unroll
    for (int i = 0; i < 8; ++i) {
        int c = cbase + i;
        float u = vs[i] * consts[c] + consts[64 + c];
        r.u[i] = f2bf(u > 0.f ? u : 0.f);
    }
    *(uint4*)(h + off) = r.v;
}

// ---------------------------------------------------------------- conv3
// y2[n] = sum_k h1[nbr[n,k]] @ W3[k], + BN2 stats. 64 pts/block.
__global__ __launch_bounds__(256) void k_conv3(const uint16_t* __restrict__ h,
        const int* __restrict__ nidx, const uint16_t* __restrict__ w3T,
        float* __restrict__ y, float* __restrict__ stats) {
    __shared__ uint16_t as_[64 * 72];   // gathered A tile, pad 64->72
    __shared__ uint16_t bs[64 * 72];    // W3T[k] tile
    __shared__ int idxs[64 * 27];
    __shared__ float ssum[64], ssq[64];
    const int t = threadIdx.x;
    const int base = blockIdx.x * 64;
    for (int i = t; i < 64 * 27; i += 256) idxs[i] = nidx[(size_t)base * 27 + i];
    if (t < 64) { ssum[t] = 0.f; ssq[t] = 0.f; }
    const int wave = t >> 6, lane = t & 63;
    const int m = lane & 15, quad = lane >> 4;
    const int gp = t >> 2, gq = (t & 3) * 16;   // 4 threads/point gather
    floatx4 zero = {0.f, 0.f, 0.f, 0.f};
    floatx4 acc[4] = {zero, zero, zero, zero};
    __syncthreads();
    for (int k = 0; k < KOFF; ++k) {
        const uint4* wsrc = (const uint4*)(w3T + k * 4096);
        uint4 w0 = wsrc[t];
        uint4 w1 = wsrc[t + 256];
        int grow = idxs[gp * 27 + k];
        const uint4* gsrc = (const uint4*)(h + (size_t)grow * 64);
        uint4 g0 = gsrc[(t & 3) * 2];
        uint4 g1 = gsrc[(t & 3) * 2 + 1];
        *(uint4*)&bs[(t >> 3) * 72 + (t & 7) * 8] = w0;
        *(uint4*)&bs[((t >> 3) + 32) * 72 + (t & 7) * 8] = w1;
        *(uint4*)&as_[gp * 72 + gq] = g0;
        *(uint4*)&as_[gp * 72 + gq + 8] = g1;
        __syncthreads();
        const uint16_t* arow = &as_[(wave * 16 + m) * 72 + quad * 8];
#pragma unroll
        for (int ks = 0; ks < 2; ++ks) {
            short8 a = *(const short8*)(arow + ks * 32);
#pragma unroll
            for (int nf = 0; nf < 4; ++nf) {
                short8 b = *(const short8*)&bs[(nf * 16 + m) * 72 + ks * 32 + quad * 8];
                acc[nf] = mfma16(a, b, acc[nf]);
            }
        }
        __syncthreads();
    }
    const int bank = blockIdx.x & 63;
    float* sb = stats + bank * 768;
#pragma unroll
    for (int nf = 0; nf < 4; ++nf) {
        float s = 0.f, q = 0.f;
#pragma unroll
        for (int r = 0; r < 4; ++r) {
            float v = acc[nf][r];
            int pt = base + wave * 16 + quad * 4 + r;
            y[(size_t)pt * 64 + nf * 16 + m] = v;
            s += v; q += v * v;
        }
        s += __shfl_xor(s, 16); q += __shfl_xor(q, 16);
        s += __shfl_xor(s, 32); q += __shfl_xor(q, 32);
        if (quad == 0) { atomicAdd(&ssum[nf * 16 + m], s); atomicAdd(&ssq[nf * 16 + m], q); }
    }
    __syncthreads();
    if (t < 64) { atomicAdd(&sb[128 + t], ssum[t]); atomicAdd(&sb[192 + t], ssq[t]); }
}

// ---------------------------------------------------------------- gemm3 (stats pass)
// h2 = bf16(relu(bn2(y2))) stored; y3 = h2 @ W1b computed for BN3 stats only.
__global__ __launch_bounds__(256) void k_gemm3(const float* __restrict__ y,
        const float* __restrict__ consts, const uint16_t* __restrict__ w1bT,
        uint16_t* __restrict__ h2, float* __restrict__ stats) {
    __shared__ uint16_t as_[64 * 72];
    __shared__ uint16_t bs[256 * 72];
    __shared__ float ssum[256], ssq[256];
    __shared__ float cf[128];
    const int t = threadIdx.x;
    const int base = blockIdx.x * 64;
    if (t < 128) cf[t] = consts[128 + t];
    ssum[t] = 0.f; ssq[t] = 0.f;
    const uint4* wsrc = (const uint4*)w1bT;
#pragma unroll
    for (int i = 0; i < 8; ++i) {
        int c = t + 256 * i;
        uint4 v = wsrc[c];
        *(uint4*)&bs[(c >> 3) * 72 + (c & 7) * 8] = v;
    }
    __syncthreads();   // cf visible
    const int r = t >> 2, cb = (t & 3) * 16;
    const float4* ysrc = (const float4*)(y + (size_t)(base + r) * 64 + cb);
    union { uint16_t u[16]; uint4 v[2]; } tmp;
#pragma unroll
    for (int j = 0; j < 4; ++j) {
        float4 v = ysrc[j];
        float vv[4] = {v.x, v.y, v.z, v.w};
#pragma unroll
        for (int e = 0; e < 4; ++e) {
            int c = cb + j * 4 + e;
            float u = vv[e] * cf[c] + cf[64 + c];
            tmp.u[j * 4 + e] = f2bf(u > 0.f ? u : 0.f);
        }
    }
    *(uint4*)&as_[r * 72 + cb] = tmp.v[0];
    *(uint4*)&as_[r * 72 + cb + 8] = tmp.v[1];
    *(uint4*)(h2 + (size_t)(base + r) * 64 + cb) = tmp.v[0];
    *(uint4*)(h2 + (size_t)(base + r) * 64 + cb + 8) = tmp.v[1];
    __syncthreads();
    const int wave = t >> 6, lane = t & 63;
    const int m = lane & 15, quad = lane >> 4;
    floatx4 zero = {0.f, 0.f, 0.f, 0.f};
    floatx4 acc[16];
#pragma unroll
    for (int i = 0; i < 16; ++i) acc[i] = zero;
    const uint16_t* arow = &as_[(wave * 16 + m) * 72 + quad * 8];
#pragma unroll
    for (int ks = 0; ks < 2; ++ks) {
        short8 a = *(const short8*)(arow + ks * 32);
#pragma unroll
        for (int nf = 0; nf < 16; ++nf) {
            short8 b = *(const short8*)&bs[(nf * 16 + m) * 72 + ks * 32 + quad * 8];
            acc[nf] = mfma16(a, b, acc[nf]);
        }
    }
    const int bank = blockIdx.x & 63;
#pragma unroll
    for (int nf = 0; nf < 16; ++nf) {
        float s = 0.f, q = 0.f;
#pragma unroll
        for (int rr = 0; rr < 4; ++rr) { float v = acc[nf][rr]; s += v; q += v * v; }
        s += __shfl_xor(s, 16); q += __shfl_xor(q, 16);
        s += __shfl_xor(s, 32); q += __shfl_xor(q, 32);
        if (quad == 0) { atomicAdd(&ssum[nf * 16 + m], s); atomicAdd(&ssq[nf * 16 + m], q); }
    }
    __syncthreads();
    atomicAdd(&stats[bank * 768 + 256 + t], ssum[t]);
    atomicAdd(&stats[bank * 768 + 512 + t], ssq[t]);
}

// ---------------------------------------------------------------- final
// Recompute y3 = h2 @ W1b, out = relu(bn3(y3) + x).
__global__ __launch_bounds__(256) void k_final(const uint16_t* __restrict__ h2,
        const uint16_t* __restrict__ w1bT, const float* __restrict__ consts,
        const float* __restrict__ x, float* __restrict__ out) {
    __shared__ uint16_t as_[64 * 72];
    __shared__ uint16_t bs[256 * 72];
    const int t = threadIdx.x;
    const int base = blockIdx.x * 64;
    const uint4* wsrc = (const uint4*)w1bT;
#pragma unroll
    for (int i = 0; i < 8; ++i) {
        int c = t + 256 * i;
        uint4 v = wsrc[c];
        *(uint4*)&bs[(c >> 3) * 72 + (c & 7) * 8] = v;
    }
    const uint4* hsrc = (const uint4*)(h2 + (size_t)base * 64);
#pragma unroll
    for (int i = 0; i < 2; ++i) {
        int c = t + 256 * i;
        uint4 v = hsrc[c];
        *(uint4*)&as_[(c >> 3) * 72 + (c & 7) * 8] = v;
    }
    __syncthreads();
    const int wave = t >> 6, lane = t & 63;
    const int m = lane & 15, quad = lane >> 4;
    floatx4 zero = {0.f, 0.f, 0.f, 0.f};
    floatx4 acc[16];
#pragma unroll
    for (int i = 0; i < 16; ++i) acc[i] = zero;
    const uint16_t* arow = &as_[(wave * 16 + m) * 72 + quad * 8];
#pragma unroll
    for (int ks = 0; ks < 2; ++ks) {
        short8 a = *(const short8*)(arow + ks * 32);
#pragma unroll
        for (int nf = 0; nf < 16; ++nf) {
            short8 b = *(const short8*)&bs[(nf * 16 + m) * 72 + ks * 32 + quad * 8];
            acc[nf] = mfma16(a, b, acc[nf]);
        }
    }
#pragma unroll
    for (int nf = 0; nf < 16; ++nf) {
        int ch = nf * 16 + m;
        float sc = consts[256 + ch], sh = consts[512 + ch];
#pragma unroll
        for (int r = 0; r < 4; ++r) {
            int pt = base + wave * 16 + quad * 4 + r;
            size_t o = (size_t)pt * 256 + ch;
            float v = acc[nf][r] * sc + sh + x[o];
            out[o] = v > 0.f ? v : 0.f;
        }
    }
}

// ---------------------------------------------------------------- launch
extern "C" void kernel_launch(void* const* d_in, const int* in_sizes, int n_in,
                              void* d_out, int out_size, void* d_ws, size_t ws_size,
                              hipStream_t stream) {
    const float* x   = (const float*)d_in[0];
    const int* nidx  = (const int*)d_in[1];
    const float* W1a = (const float*)d_in[2];
    const float* g1a = (const float*)d_in[3];
    const float* b1a = (const float*)d_in[4];
    const float* W3  = (const float*)d_in[5];
    const float* g3  = (const float*)d_in[6];
    const float* b3  = (const float*)d_in[7];
    const float* W1b = (const float*)d_in[8];
    const float* g1b = (const float*)d_in[9];
    const float* b1b = (const float*)d_in[10];
    float* out = (float*)d_out;

    // workspace layout (~97 MB)
    float* y = (float*)d_ws;                              // N*64 f32 (y1 then y2)
    uint16_t* h = (uint16_t*)(y + (size_t)NPTS * 64);     // N*64 bf16 (h1 then h2)
    uint16_t* w1aT = h + (size_t)NPTS * 64;               // 64*256
    uint16_t* w3T  = w1aT + 64 * 256;                     // 27*64*64
    uint16_t* w1bT = w3T + KOFF * 64 * 64;                // 256*64
    float* stats  = (float*)(w1bT + 256 * 64);            // 64 banks * 768
    float* consts = stats + 64 * 768;                     // 768 scale/shift

    k_prep<<<64, 256, 0, stream>>>(W1a, W3, W1b, w1aT, w3T, w1bT, stats);
    k_gemm1<<<NPTS / 64, 256, 0, stream>>>(x, w1aT, y, stats);
    k_fin<<<1, 64, 0, stream>>>(stats, g1a, b1a, consts, 64, 0, 0);
    k_bnrelu<<<NPTS * 64 / (256 * 8), 256, 0, stream>>>(y, consts, h);
    k_conv3<<<NPTS / 64, 256, 0, stream>>>(h, nidx, w3T, y, stats);
    k_fin<<<1, 64, 0, stream>>>(stats, g3, b3, consts, 64, 128, 128);
    k_gemm3<<<NPTS / 64, 256, 0, stream>>>(y, consts, w1bT, h, stats);
    k_fin<<<1, 256, 0, stream>>>(stats, g1b, b1b, consts, 256, 256, 256);
    k_final<<<NPTS / 64, 256, 0, stream>>>(h, w1bT, consts, x, out);
}